// Round 7
// baseline (4319.015 us; speedup 1.0000x reference)
//
#include <hip/hip_runtime.h>
#include <cstdint>
#include <cstddef>

using u16 = unsigned short;
using bf16x8 = __attribute__((ext_vector_type(8))) short;
using f32x4  = __attribute__((ext_vector_type(4))) float;

__device__ __forceinline__ u16 f2bf(float f) {
  unsigned u = __float_as_uint(f);
  u += 0x7fffu + ((u >> 16) & 1u);
  return (u16)(u >> 16);
}
__device__ __forceinline__ float bf2f(u16 h) {
  return __uint_as_float(((unsigned)h) << 16);
}

__device__ __forceinline__ void gload_lds16(const void* g, void* l) {
  auto gp = reinterpret_cast<const __attribute__((address_space(1))) char*>(
      reinterpret_cast<uintptr_t>(g));
  auto lp = reinterpret_cast<__attribute__((address_space(3))) char*>(
      reinterpret_cast<uintptr_t>(l));
  __builtin_amdgcn_global_load_lds(gp, lp, 16, 0, 0);
}

// ---------- weight transpose + downcast: W f32[din][dout] -> WT bf16[dout][din]
__global__ __launch_bounds__(256) void transpose_to_bf16(
    const float* __restrict__ W, u16* __restrict__ WT, int din, int dout) {
  __shared__ float tile[32][33];
  const int j0 = blockIdx.x * 32;   // dout
  const int i0 = blockIdx.y * 32;   // din
  const int tx = threadIdx.x & 31;
  const int ty = threadIdx.x >> 5;  // 0..7
#pragma unroll
  for (int k = 0; k < 32; k += 8)
    tile[ty + k][tx] = W[(size_t)(i0 + ty + k) * dout + (j0 + tx)];
  __syncthreads();
#pragma unroll
  for (int k = 0; k < 32; k += 8)
    WT[(size_t)(j0 + ty + k) * din + (i0 + tx)] = f2bf(tile[tx][ty + k]);
}

// ---------- rmsnorm f32 -> bf16, one block per row of 1024
__global__ __launch_bounds__(256) void rmsnorm_kernel(
    const float* __restrict__ x, const float* __restrict__ g, u16* __restrict__ xn) {
  const int row = blockIdx.x;
  const float4 v = ((const float4*)(x + (size_t)row * 1024))[threadIdx.x];
  float ss = v.x * v.x + v.y * v.y + v.z * v.z + v.w * v.w;
#pragma unroll
  for (int off = 32; off > 0; off >>= 1) ss += __shfl_down(ss, off, 64);
  __shared__ float red[4];
  if ((threadIdx.x & 63) == 0) red[threadIdx.x >> 6] = ss;
  __syncthreads();
  const float rs = rsqrtf((red[0] + red[1] + red[2] + red[3]) * (1.f / 1024.f) + 1e-6f);
  const float4 gv = ((const float4*)g)[threadIdx.x];
  ushort4 o;
  o.x = f2bf(v.x * rs * gv.x);
  o.y = f2bf(v.y * rs * gv.y);
  o.z = f2bf(v.z * rs * gv.z);
  o.w = f2bf(v.w * rs * gv.w);
  ((ushort4*)(xn + (size_t)row * 1024))[threadIdx.x] = o;
}

// ---------- chunked linear-recurrence scan: h[l] = sig(-dt)*h[l-1] + sig(dt)*sig(lnz)
__global__ __launch_bounds__(256) void scan_pass1(
    const u16* __restrict__ dt, const u16* __restrict__ lnz,
    float* __restrict__ P, float* __restrict__ S) {
  const int blk = blockIdx.x;              // B*64*4 = 1024 blocks
  const int dblk = blk & 3;
  const int chunk = (blk >> 2) & 63;
  const int b = blk >> 8;
  const int d = dblk * 256 + threadIdx.x;
  const size_t base = ((size_t)b * 4096 + (size_t)chunk * 64) * 1024 + d;
  float p = 1.f, s = 0.f;
#pragma unroll 8
  for (int l = 0; l < 64; ++l) {
    const float dtv = bf2f(dt[base + (size_t)l * 1024]);
    const float zv = bf2f(lnz[base + (size_t)l * 1024]);
    const float a = 1.f / (1.f + __expf(dtv));        // sigmoid(-dt)
    const float zs = 1.f / (1.f + __expf(-zv));       // sigmoid(lnz_pre)
    const float in = (1.f - a) * zs;
    p *= a;
    s = a * s + in;
  }
  const size_t o = ((size_t)b * 64 + chunk) * 1024 + d;
  P[o] = p;
  S[o] = s;
}

__global__ __launch_bounds__(256) void scan_pass2(
    const float* __restrict__ P, const float* __restrict__ S,
    const float* __restrict__ hidden, float* __restrict__ hin) {
  const int idx = blockIdx.x * 256 + threadIdx.x;  // 0..4095
  const int b = idx >> 10, d = idx & 1023;
  float h = hidden[idx];
#pragma unroll 8
  for (int c = 0; c < 64; ++c) {
    const size_t o = ((size_t)b * 64 + c) * 1024 + d;
    hin[o] = h;
    h = P[o] * h + S[o];
  }
}

__global__ __launch_bounds__(256) void scan_pass3(
    const u16* __restrict__ dt, const u16* __restrict__ lnz,
    const float* __restrict__ hin, float* __restrict__ h_out, u16* __restrict__ hbf) {
  const int blk = blockIdx.x;
  const int dblk = blk & 3;
  const int chunk = (blk >> 2) & 63;
  const int b = blk >> 8;
  const int d = dblk * 256 + threadIdx.x;
  const size_t base = ((size_t)b * 4096 + (size_t)chunk * 64) * 1024 + d;
  float h = hin[((size_t)b * 64 + chunk) * 1024 + d];
#pragma unroll 4
  for (int l = 0; l < 64; ++l) {
    const float dtv = bf2f(dt[base + (size_t)l * 1024]);
    const float zv = bf2f(lnz[base + (size_t)l * 1024]);
    const float a = 1.f / (1.f + __expf(dtv));
    const float zs = 1.f / (1.f + __expf(-zv));
    h = a * h + (1.f - a) * zs;
    h_out[base + (size_t)l * 1024] = h;
    hbf[base + (size_t)l * 1024] = f2bf(h);
  }
}

// ---------- 256x256 GEMM, 2-blocks/CU TLP schedule: C = A[M][K] @ B^T (bf16).
// 8 waves (2Mx4N), per-wave 128x64 out, BK=64. Ring of FIVE half-tile LDS
// slots (80 KiB) so TWO blocks fit per CU (launch_bounds(512,4), VGPR<=128):
// cross-block implicit overlap hides the tile-end vmcnt(0) drain (m114/m97
// mechanism) instead of deep in-block prefetch.
// Slot audit (slot = half % 5): during tile t,
//  - STAGE A0(t+1) at ph0 -> slot (4t+4)%5 == B1(t-1), dead since t start
//    (t-1 end barrier).
//  - STAGE A1/B0/B1(t+1) after the mid barrier -> slots (4t)%5,(4t+1)%5,
//    (4t+2)%5 == A0/A1/B0(t), whose reads (ph0/ph2/ph1) all precede the
//    mid barrier.
//  - vmcnt(0)+barrier at tile end -> tile t+1 fully resident.
// EPI: 5 = fused3: bf16 outs {outH=dt, outH2=lnz, outH3=yg}, row stride 1024
//      2 = f32 out = (acc+b)*silu(gate bf16) + resid
//      6 = bf16 out = silu(acc+b)
//      7 = bf16 out = (acc+b)*bf2f(gate)   (gate may alias outH: in-place)
//      4 = f32 out = acc + b + outF (in-place residual add)
template <int EPI>
__global__ __launch_bounds__(512, 4) void gemm256(
    const u16* __restrict__ A, const u16* __restrict__ B,
    const float* __restrict__ bias, const u16* __restrict__ gate,
    const float* __restrict__ resid, float* __restrict__ outF,
    u16* __restrict__ outH, u16* __restrict__ outH2, u16* __restrict__ outH3,
    int ntx, int N, int K) {
  constexpr int SLOT = 16384;
  const int tid = threadIdx.x;
  const int lane = tid & 63;
  const int wid = tid >> 6;
  const int wr = wid >> 2;   // 0..1 -> A half
  const int wc = wid & 3;    // 0..3 -> 64-col strip; wc>>1 -> B half

  // XCD-aware swizzle (grid %8==0 for all our launches)
  const int nwg = gridDim.x;
  int id = blockIdx.x;
  id = (id & 7) * (nwg >> 3) + (id >> 3);
  const int m0 = (id / ntx) * 256;
  const int n0 = (id % ntx) * 256;

  __shared__ __align__(16) char lds[5 * SLOT];

  f32x4 acc[8][4];
#pragma unroll
  for (int m = 0; m < 8; ++m)
#pragma unroll
    for (int n = 0; n < 4; ++n) acc[m][n] = (f32x4){0.f, 0.f, 0.f, 0.f};

  bf16x8 aR[4][2], bR[4][2];

  // ---- hoisted LDS read offsets (relative to slot base) ----
  int aOff[4][2], bOff[2][2];
  {
    const int lq = (lane >> 4) << 4;
#pragma unroll
    for (int m = 0; m < 4; ++m) {
      const int hr = m * 16 + (lane & 15);
#pragma unroll
      for (int k = 0; k < 2; ++k)
        aOff[m][k] = hr * 128 + ((k * 64 + lq) ^ ((hr & 7) << 4));
    }
#pragma unroll
    for (int n = 0; n < 2; ++n) {
      const int hr = (wc & 1) * 64 + n * 16 + (lane & 15);
#pragma unroll
      for (int k = 0; k < 2; ++k)
        bOff[n][k] = hr * 128 + ((k * 64 + lq) ^ ((hr & 7) << 4));
    }
  }

  // ---- hoisted stage addressing ----
  const int row0 = tid >> 3;                               // 0..63
  const int kb0  = ((tid & 7) * 16) ^ ((row0 & 7) << 4);   // inverse-swizzled src byte
  const size_t dRow = (size_t)128 * K;                     // +64 rows (bytes)
  const char* pA0 = (const char*)A + (size_t)(m0 + row0) * K * 2 + kb0;
  const char* pA1 = pA0 + (size_t)256 * K;                 // +128 rows
  const char* pB0 = (const char*)B + (size_t)(n0 + row0) * K * 2 + kb0;
  const char* pB1 = pB0 + (size_t)256 * K;
  const int ldst = tid * 16;                               // LDS offset within slot

#define STAGE(PTR, SB)                                                        \
  {                                                                           \
    gload_lds16(PTR, lds + (SB) + ldst);                                      \
    gload_lds16(PTR + dRow, lds + (SB) + ldst + 8192);                        \
    PTR += 128;                                                               \
  }

#define READA(SAB, QM)                                                        \
  _Pragma("unroll") for (int m = 0; m < 4; ++m)                               \
  _Pragma("unroll") for (int k = 0; k < 2; ++k)                               \
    aR[m][k] = *(const bf16x8*)(lds + (SAB) + aOff[m][k] + (QM) * 8192);

#define READB(SBB, NP)                                                        \
  _Pragma("unroll") for (int n = 0; n < 2; ++n)                               \
  _Pragma("unroll") for (int k = 0; k < 2; ++k)                               \
    bR[(NP) + n][k] = *(const bf16x8*)(lds + (SBB) + bOff[n][k] + (NP) * 2048);

#define MMAQ(QM, QN)                                                          \
  __builtin_amdgcn_s_setprio(1);                                              \
  _Pragma("unroll") for (int m = 0; m < 4; ++m)                               \
  _Pragma("unroll") for (int n = 0; n < 2; ++n)                               \
  _Pragma("unroll") for (int k = 0; k < 2; ++k)                               \
      acc[(QM) * 4 + m][(QN) * 2 + n] = __builtin_amdgcn_mfma_f32_16x16x32_bf16( \
          aR[m][k], bR[(QN) * 2 + n][k], acc[(QM) * 4 + m][(QN) * 2 + n], 0, 0, 0); \
  __builtin_amdgcn_s_setprio(0);

  const int NT = K >> 6;

  // prologue: tile0's 4 halves -> slots 0..3 (slot 4 filled in-loop)
  STAGE(pA0, 0 * SLOT);
  STAGE(pA1, 1 * SLOT);
  STAGE(pB0, 2 * SLOT);
  STAGE(pB1, 3 * SLOT);
  asm volatile("s_waitcnt vmcnt(0)" ::: "memory");
  __builtin_amdgcn_s_barrier();

  int iA = wr;             // slot of this wave's A half, advances +4 mod 5
  int iB = 2 + (wc >> 1);  // slot of this wave's B half
  int iS = 4;              // slot for A0(t+1)

  for (int t = 0; t < NT; ++t) {
    const int sAb = __builtin_amdgcn_readfirstlane(iA * SLOT);
    const int sBb = __builtin_amdgcn_readfirstlane(iB * SLOT);
    int s0 = iS * SLOT;
    int s1 = s0 + SLOT; if (s1 >= 5 * SLOT) s1 -= 5 * SLOT;
    int s2 = s1 + SLOT; if (s2 >= 5 * SLOT) s2 -= 5 * SLOT;
    int s3 = s2 + SLOT; if (s3 >= 5 * SLOT) s3 -= 5 * SLOT;
    const bool st = (t < NT - 1);
    // free-flowing span: reads + 48 MFMA
    READA(sAb, 0);
    READB(sBb, 0);
    if (st) STAGE(pA0, s0);          // slot == B1(t-1), dead since t start
    MMAQ(0, 0);
    READB(sBb, 2);
    MMAQ(0, 1);
    READA(sAb, 1);
    MMAQ(1, 0);
    // mid barrier: all waves' reads of tile t's slots are complete.
    __builtin_amdgcn_s_barrier();
    if (st) {
      STAGE(pA1, s1);                // overwrite A0(t)/A1(t)/B0(t) slots
      STAGE(pB0, s2);
      STAGE(pB1, s3);
    }
    MMAQ(1, 1);
    asm volatile("s_waitcnt vmcnt(0)" ::: "memory");
    __builtin_amdgcn_s_barrier();
    iA += 4; if (iA >= 5) iA -= 5;
    iB += 4; if (iB >= 5) iB -= 5;
    iS += 4; if (iS >= 5) iS -= 5;
  }

  // epilogue: C/D layout col = lane&15, row = (lane>>4)*4 + j
#pragma unroll
  for (int m = 0; m < 8; ++m) {
#pragma unroll
    for (int n = 0; n < 4; ++n) {
      const int col = n0 + wc * 64 + n * 16 + (lane & 15);
#pragma unroll
      for (int j = 0; j < 4; ++j) {
        const int row = m0 + wr * 128 + m * 16 + ((lane >> 4) << 2) + j;
        const float v = acc[m][n][j] + bias[col];
        if constexpr (EPI == 5) {
          const int rg = col >> 10;                     // block-uniform
          const size_t o = (size_t)row * 1024 + (col & 1023);
          if (rg == 0) outH[o] = f2bf(v);
          else if (rg == 1) outH2[o] = f2bf(v);
          else outH3[o] = f2bf(v);
        } else {
          const size_t o = (size_t)row * N + col;
          if constexpr (EPI == 2) {
            const float gt = bf2f(gate[o]);
            outF[o] = v * (gt / (1.f + __expf(-gt))) + resid[o];
          } else if constexpr (EPI == 6) {
            outH[o] = f2bf(v / (1.f + __expf(-v)));
          } else if constexpr (EPI == 7) {
            outH[o] = f2bf(v * bf2f(gate[o]));          // gate==outH ok (RAW per elem)
          } else if constexpr (EPI == 4) {
            outF[o] = v + outF[o];
          }
        }
      }
    }
  }
#undef STAGE
#undef READA
#undef READB
#undef MMAQ
}

extern "C" void kernel_launch(void* const* d_in, const int* in_sizes, int n_in,
                              void* d_out, int out_size, void* d_ws, size_t ws_size,
                              hipStream_t stream) {
  const float* x      = (const float*)d_in[0];
  const float* hidden = (const float*)d_in[1];
  const float* w_ln_z = (const float*)d_in[2];
  const float* b_ln_z = (const float*)d_in[3];
  const float* w_dt   = (const float*)d_in[4];
  const float* b_dt   = (const float*)d_in[5];
  const float* w_y    = (const float*)d_in[6];
  const float* b_y    = (const float*)d_in[7];
  const float* w_yg   = (const float*)d_in[8];
  const float* b_yg   = (const float*)d_in[9];
  const float* w_ff   = (const float*)d_in[10];
  const float* b_ff   = (const float*)d_in[11];
  const float* w_ffg  = (const float*)d_in[12];
  const float* b_ffg  = (const float*)d_in[13];
  const float* w_ffo  = (const float*)d_in[14];
  const float* b_ffo  = (const float*)d_in[15];
  const float* g_sio  = (const float*)d_in[16];
  const float* g_ffn  = (const float*)d_in[17];

  char* ws = (char*)d_ws;
  const size_t MB = 1ull << 20;
  u16*   WT_cat = (u16*)(ws + 0 * MB);      // 6 MiB  [3072][1024] (dt|lnz|yg)
  u16*   WT_y   = (u16*)(ws + 8 * MB);      // 2 MiB
  u16*   WT_ff  = (u16*)(ws + 10 * MB);     // 8 MiB  [4096][1024]
  u16*   WT_ffg = (u16*)(ws + 18 * MB);     // 8 MiB
  u16*   WT_ffo = (u16*)(ws + 26 * MB);     // 8 MiB  [1024][4096]
  float* b_cat  = (float*)(ws + 34 * MB);   // 12 KiB [3072]
  u16*   xn     = (u16*)(ws + 36 * MB);     // 32 MiB [16384][1024] bf16
  u16*   dt16   = (u16*)(ws + 68 * MB);     // 32 MiB bf16
  u16*   lnzb   = (u16*)(ws + 100 * MB);    // 32 MiB
  u16*   ygb    = (u16*)(ws + 132 * MB);    // 32 MiB
  u16*   hbf    = (u16*)(ws + 164 * MB);    // 32 MiB
  float* Pc     = (float*)(ws + 196 * MB);  // 1 MiB
  float* Sc     = (float*)(ws + 197 * MB);  // 1 MiB
  float* hin    = (float*)(ws + 198 * MB);  // 1 MiB
  u16*   gs     = (u16*)(ws + 68 * MB);     // 128 MiB overlay [16384][4096]
  // peak ws usage: 199 MiB

  float* x_out = (float*)d_out;
  float* h_out = (float*)d_out + (size_t)4 * 4096 * 1024;

  const int M = 16384, D = 1024, F = 4096;
  const dim3 tb(256);

  transpose_to_bf16<<<dim3(32, 32), tb, 0, stream>>>(w_dt, WT_cat, D, D);
  transpose_to_bf16<<<dim3(32, 32), tb, 0, stream>>>(w_ln_z, WT_cat + 1024 * 1024, D, D);
  transpose_to_bf16<<<dim3(32, 32), tb, 0, stream>>>(w_yg, WT_cat + 2 * 1024 * 1024, D, D);
  transpose_to_bf16<<<dim3(32, 32), tb, 0, stream>>>(w_y, WT_y, D, D);
  transpose_to_bf16<<<dim3(128, 32), tb, 0, stream>>>(w_ff, WT_ff, D, F);
  transpose_to_bf16<<<dim3(128, 32), tb, 0, stream>>>(w_ffg, WT_ffg, D, F);
  transpose_to_bf16<<<dim3(32, 128), tb, 0, stream>>>(w_ffo, WT_ffo, F, D);
  (void)hipMemcpyAsync(b_cat, b_dt, D * 4, hipMemcpyDeviceToDevice, stream);
  (void)hipMemcpyAsync(b_cat + 1024, b_ln_z, D * 4, hipMemcpyDeviceToDevice, stream);
  (void)hipMemcpyAsync(b_cat + 2048, b_yg, D * 4, hipMemcpyDeviceToDevice, stream);

  rmsnorm_kernel<<<M, tb, 0, stream>>>(x, g_sio, xn);

  // fused dt|lnz|yg GEMM: N=3072
  gemm256<5><<<dim3(12 * 64), 512, 0, stream>>>(xn, WT_cat, b_cat, nullptr, nullptr,
                                                nullptr, dt16, lnzb, ygb, 12, 3072, D);

  scan_pass1<<<1024, tb, 0, stream>>>(dt16, lnzb, Pc, Sc);
  scan_pass2<<<16, tb, 0, stream>>>(Pc, Sc, hidden, hin);
  scan_pass3<<<1024, tb, 0, stream>>>(dt16, lnzb, hin, h_out, hbf);

  // x1 = (h@w_y + b_y) * silu(yg) + x
  gemm256<2><<<dim3(4 * 64), 512, 0, stream>>>(hbf, WT_y, b_y, ygb, x,
                                               x_out, nullptr, nullptr, nullptr, 4, D, D);

  rmsnorm_kernel<<<M, tb, 0, stream>>>(x_out, g_ffn, xn);

  // gs = silu(xn@w_ffg + b_ffg)
  gemm256<6><<<dim3(16 * 64), 512, 0, stream>>>(xn, WT_ffg, b_ffg, nullptr, nullptr,
                                                nullptr, gs, nullptr, nullptr, 16, F, D);
  // gs = (xn@w_ff + b_ff) * gs   (in-place gated mul)
  gemm256<7><<<dim3(16 * 64), 512, 0, stream>>>(xn, WT_ff, b_ff, gs, nullptr,
                                                nullptr, gs, nullptr, nullptr, 16, F, D);
  // x_out += gs@w_ffo + b_ffo
  gemm256<4><<<dim3(4 * 64), 512, 0, stream>>>(gs, WT_ffo, b_ffo, nullptr, nullptr,
                                               x_out, nullptr, nullptr, nullptr, 4, D, F);
}

// Round 8
// 778.309 us; speedup vs baseline: 5.5492x; 5.5492x over previous
//
#include <hip/hip_runtime.h>
#include <cstdint>
#include <cstddef>

using u16 = unsigned short;
using bf16x8 = __attribute__((ext_vector_type(8))) short;
using f32x4  = __attribute__((ext_vector_type(4))) float;

__device__ __forceinline__ u16 f2bf(float f) {
  unsigned u = __float_as_uint(f);
  u += 0x7fffu + ((u >> 16) & 1u);
  return (u16)(u >> 16);
}
__device__ __forceinline__ float bf2f(u16 h) {
  return __uint_as_float(((unsigned)h) << 16);
}

__device__ __forceinline__ void gload_lds16(const void* g, void* l) {
  auto gp = reinterpret_cast<const __attribute__((address_space(1))) char*>(
      reinterpret_cast<uintptr_t>(g));
  auto lp = reinterpret_cast<__attribute__((address_space(3))) char*>(
      reinterpret_cast<uintptr_t>(l));
  __builtin_amdgcn_global_load_lds(gp, lp, 16, 0, 0);
}

// ---------- weight transpose + downcast: W f32[din][dout] -> WT bf16[dout][din]
__global__ __launch_bounds__(256) void transpose_to_bf16(
    const float* __restrict__ W, u16* __restrict__ WT, int din, int dout) {
  __shared__ float tile[32][33];
  const int j0 = blockIdx.x * 32;   // dout
  const int i0 = blockIdx.y * 32;   // din
  const int tx = threadIdx.x & 31;
  const int ty = threadIdx.x >> 5;  // 0..7
#pragma unroll
  for (int k = 0; k < 32; k += 8)
    tile[ty + k][tx] = W[(size_t)(i0 + ty + k) * dout + (j0 + tx)];
  __syncthreads();
#pragma unroll
  for (int k = 0; k < 32; k += 8)
    WT[(size_t)(j0 + ty + k) * din + (i0 + tx)] = f2bf(tile[tx][ty + k]);
}

// ---------- rmsnorm f32 -> bf16, one block per row of 1024
__global__ __launch_bounds__(256) void rmsnorm_kernel(
    const float* __restrict__ x, const float* __restrict__ g, u16* __restrict__ xn) {
  const int row = blockIdx.x;
  const float4 v = ((const float4*)(x + (size_t)row * 1024))[threadIdx.x];
  float ss = v.x * v.x + v.y * v.y + v.z * v.z + v.w * v.w;
#pragma unroll
  for (int off = 32; off > 0; off >>= 1) ss += __shfl_down(ss, off, 64);
  __shared__ float red[4];
  if ((threadIdx.x & 63) == 0) red[threadIdx.x >> 6] = ss;
  __syncthreads();
  const float rs = rsqrtf((red[0] + red[1] + red[2] + red[3]) * (1.f / 1024.f) + 1e-6f);
  const float4 gv = ((const float4*)g)[threadIdx.x];
  ushort4 o;
  o.x = f2bf(v.x * rs * gv.x);
  o.y = f2bf(v.y * rs * gv.y);
  o.z = f2bf(v.z * rs * gv.z);
  o.w = f2bf(v.w * rs * gv.w);
  ((ushort4*)(xn + (size_t)row * 1024))[threadIdx.x] = o;
}

// ---------- chunked linear-recurrence scan: h[l] = sig(-dt)*h[l-1] + sig(dt)*sig(lnz)
__global__ __launch_bounds__(256) void scan_pass1(
    const u16* __restrict__ dt, const u16* __restrict__ lnz,
    float* __restrict__ P, float* __restrict__ S) {
  const int blk = blockIdx.x;              // B*64*4 = 1024 blocks
  const int dblk = blk & 3;
  const int chunk = (blk >> 2) & 63;
  const int b = blk >> 8;
  const int d = dblk * 256 + threadIdx.x;
  const size_t base = ((size_t)b * 4096 + (size_t)chunk * 64) * 1024 + d;
  float p = 1.f, s = 0.f;
#pragma unroll 8
  for (int l = 0; l < 64; ++l) {
    const float dtv = bf2f(dt[base + (size_t)l * 1024]);
    const float zv = bf2f(lnz[base + (size_t)l * 1024]);
    const float a = 1.f / (1.f + __expf(dtv));        // sigmoid(-dt)
    const float zs = 1.f / (1.f + __expf(-zv));       // sigmoid(lnz_pre)
    const float in = (1.f - a) * zs;
    p *= a;
    s = a * s + in;
  }
  const size_t o = ((size_t)b * 64 + chunk) * 1024 + d;
  P[o] = p;
  S[o] = s;
}

__global__ __launch_bounds__(256) void scan_pass2(
    const float* __restrict__ P, const float* __restrict__ S,
    const float* __restrict__ hidden, float* __restrict__ hin) {
  const int idx = blockIdx.x * 256 + threadIdx.x;  // 0..4095
  const int b = idx >> 10, d = idx & 1023;
  float h = hidden[idx];
#pragma unroll 8
  for (int c = 0; c < 64; ++c) {
    const size_t o = ((size_t)b * 64 + c) * 1024 + d;
    hin[o] = h;
    h = P[o] * h + S[o];
  }
}

__global__ __launch_bounds__(256) void scan_pass3(
    const u16* __restrict__ dt, const u16* __restrict__ lnz,
    const float* __restrict__ hin, float* __restrict__ h_out, u16* __restrict__ hbf) {
  const int blk = blockIdx.x;
  const int dblk = blk & 3;
  const int chunk = (blk >> 2) & 63;
  const int b = blk >> 8;
  const int d = dblk * 256 + threadIdx.x;
  const size_t base = ((size_t)b * 4096 + (size_t)chunk * 64) * 1024 + d;
  float h = hin[((size_t)b * 64 + chunk) * 1024 + d];
#pragma unroll 4
  for (int l = 0; l < 64; ++l) {
    const float dtv = bf2f(dt[base + (size_t)l * 1024]);
    const float zv = bf2f(lnz[base + (size_t)l * 1024]);
    const float a = 1.f / (1.f + __expf(dtv));
    const float zs = 1.f / (1.f + __expf(-zv));
    h = a * h + (1.f - a) * zs;
    h_out[base + (size_t)l * 1024] = h;
    hbf[base + (size_t)l * 1024] = f2bf(h);
  }
}

// ---------- 256x256 GEMM: C[M][N] = A[M][K] @ B^T, B stored [N][K] bf16.
// 8 waves (2Mx4N), per-wave 128x64 out, BK=64, ring of 10 half-tile LDS
// slots (160 KiB), lead = 3 half-tiles, counted vmcnt(6).
// SCHED=0: R6 relaxed 2-barrier body (control).
// SCHED=1: front-loaded reads probe — issue A-QM0 + ALL B reads before the
//   first MFMA burst so the LDS queue services under MFMA; READA(QM1) under
//   the MMAQ(0,*) burst; ALL 4 stages after the mid barrier; vmcnt(6); barrier.
//   Slot-overwrite audit: B1(t+1)/A0(t+2)/A1(t+2) overwrite t-1 halves (dead
//   two barriers ago); B0(t+2) overwrites A0(t) whose reads are consumed by
//   pre-barrier MFMAs of this tile.
// EPI: 5 = fused3: bf16 outs {outH=dt, outH2=lnz, outH3=yg}, row stride 1024
//      2 = f32 out = (acc+b)*silu(gate bf16) + resid
//      6 = bf16 out = silu(acc+b)
//      7 = bf16 out = (acc+b)*bf2f(gate)   (gate may alias outH: in-place)
//      4 = f32 out = acc + b + outF (in-place residual add)
template <int EPI, int SCHED>
__global__ __launch_bounds__(512, 2) void gemm256(
    const u16* __restrict__ A, const u16* __restrict__ B,
    const float* __restrict__ bias, const u16* __restrict__ gate,
    const float* __restrict__ resid, float* __restrict__ outF,
    u16* __restrict__ outH, u16* __restrict__ outH2, u16* __restrict__ outH3,
    int ntx, int N, int K) {
  constexpr int SLOT = 16384;
  constexpr int LDSZ = 10 * SLOT;
  const int tid = threadIdx.x;
  const int lane = tid & 63;
  const int wid = tid >> 6;
  const int wr = wid >> 2;   // 0..1 -> A half
  const int wc = wid & 3;    // 0..3 -> 64-col strip; wc>>1 -> B half

  // XCD-aware swizzle (grid %8==0 for all our launches)
  const int nwg = gridDim.x;
  int id = blockIdx.x;
  id = (id & 7) * (nwg >> 3) + (id >> 3);
  const int m0 = (id / ntx) * 256;
  const int n0 = (id % ntx) * 256;

  __shared__ __align__(16) char lds[LDSZ];

  f32x4 acc[8][4];
#pragma unroll
  for (int m = 0; m < 8; ++m)
#pragma unroll
    for (int n = 0; n < 4; ++n) acc[m][n] = (f32x4){0.f, 0.f, 0.f, 0.f};

  bf16x8 aR[4][2], bR[4][2];

  // ---- hoisted LDS read offsets (relative to slot base) ----
  int aOff[4][2], bOff[2][2];
  {
    const int lq = (lane >> 4) << 4;
#pragma unroll
    for (int m = 0; m < 4; ++m) {
      const int hr = m * 16 + (lane & 15);
#pragma unroll
      for (int k = 0; k < 2; ++k)
        aOff[m][k] = hr * 128 + ((k * 64 + lq) ^ ((hr & 7) << 4));
    }
#pragma unroll
    for (int n = 0; n < 2; ++n) {
      const int hr = (wc & 1) * 64 + n * 16 + (lane & 15);
#pragma unroll
      for (int k = 0; k < 2; ++k)
        bOff[n][k] = hr * 128 + ((k * 64 + lq) ^ ((hr & 7) << 4));
    }
  }

  // ---- hoisted stage addressing ----
  const int row0 = tid >> 3;                               // 0..63
  const int kb0  = ((tid & 7) * 16) ^ ((row0 & 7) << 4);   // inverse-swizzled src byte
  const size_t dRow = (size_t)128 * K;                     // +64 rows (bytes)
  const char* pA0 = (const char*)A + (size_t)(m0 + row0) * K * 2 + kb0;
  const char* pA1 = pA0 + (size_t)256 * K;                 // +128 rows
  const char* pB0 = (const char*)B + (size_t)(n0 + row0) * K * 2 + kb0;
  const char* pB1 = pB0 + (size_t)256 * K;
  const int ldst = tid * 16;                               // LDS offset within slot

#define STAGE(PTR, SB)                                                        \
  {                                                                           \
    gload_lds16(PTR, lds + (SB) + ldst);                                      \
    gload_lds16(PTR + dRow, lds + (SB) + ldst + 8192);                        \
    PTR += 128;                                                               \
  }

#define READA(SAB, QM)                                                        \
  _Pragma("unroll") for (int m = 0; m < 4; ++m)                               \
  _Pragma("unroll") for (int k = 0; k < 2; ++k)                               \
    aR[m][k] = *(const bf16x8*)(lds + (SAB) + aOff[m][k] + (QM) * 8192);

#define READB(SBB, NP)                                                        \
  _Pragma("unroll") for (int n = 0; n < 2; ++n)                               \
  _Pragma("unroll") for (int k = 0; k < 2; ++k)                               \
    bR[(NP) + n][k] = *(const bf16x8*)(lds + (SBB) + bOff[n][k] + (NP) * 2048);

#define MMAQ(QM, QN)                                                          \
  __builtin_amdgcn_s_setprio(1);                                              \
  _Pragma("unroll") for (int m = 0; m < 4; ++m)                               \
  _Pragma("unroll") for (int n = 0; n < 2; ++n)                               \
  _Pragma("unroll") for (int k = 0; k < 2; ++k)                               \
      acc[(QM) * 4 + m][(QN) * 2 + n] = __builtin_amdgcn_mfma_f32_16x16x32_bf16( \
          aR[m][k], bR[(QN) * 2 + n][k], acc[(QM) * 4 + m][(QN) * 2 + n], 0, 0, 0); \
  __builtin_amdgcn_s_setprio(0);

  const int NT = K >> 6;

  // prologue: halves 0..6 -> slots 0..6 (tile0 complete + tile1 A0,A1,B0)
  STAGE(pA0, 0 * SLOT);
  STAGE(pA1, 1 * SLOT);
  STAGE(pB0, 2 * SLOT);
  STAGE(pB1, 3 * SLOT);
  STAGE(pA0, 4 * SLOT);
  STAGE(pA1, 5 * SLOT);
  STAGE(pB0, 6 * SLOT);
  asm volatile("s_waitcnt vmcnt(6)" ::: "memory");   // tile0 resident, 3 halves in flight
  __builtin_amdgcn_s_barrier();

  int iA = wr;             // slot of this wave's A half, advances +4 mod 10
  int iB = 2 + (wc >> 1);  // slot of this wave's B half
  int iS = 7;              // stage slot for B1(t+1)

  for (int t = 0; t < NT; ++t) {
    const int sAb = __builtin_amdgcn_readfirstlane(iA * SLOT);
    const int sBb = __builtin_amdgcn_readfirstlane(iB * SLOT);
    int s0 = iS * SLOT;
    int s1 = s0 + SLOT; if (s1 >= LDSZ) s1 -= LDSZ;
    int s2 = s1 + SLOT; if (s2 >= LDSZ) s2 -= LDSZ;
    int s3 = s2 + SLOT; if (s3 >= LDSZ) s3 -= LDSZ;
    const bool st0 = (t <= NT - 2);     // stage B1 of tile t+1
    const bool st123 = (t <= NT - 3);   // stage A0/A1/B0 of tile t+2

    if constexpr (SCHED == 0) {
      // control: R6 relaxed body
      READA(sAb, 0);
      READB(sBb, 0);
      if (st0) STAGE(pB1, s0);
      MMAQ(0, 0);
      READB(sBb, 2);
      if (st123) STAGE(pA0, s1);
      MMAQ(0, 1);
      READA(sAb, 1);
      if (st123) STAGE(pA1, s2);
      MMAQ(1, 0);
      __builtin_amdgcn_s_barrier();
      if (st123) STAGE(pB0, s3);
      MMAQ(1, 1);
    } else {
      // probe: front-loaded reads, stages all post-barrier
      READA(sAb, 0);
      READB(sBb, 0);
      READB(sBb, 2);
      MMAQ(0, 0);
      MMAQ(0, 1);
      READA(sAb, 1);
      MMAQ(1, 0);
      MMAQ(1, 1);
      __builtin_amdgcn_s_barrier();
      if (st0) STAGE(pB1, s0);
      if (st123) {
        STAGE(pA0, s1);
        STAGE(pA1, s2);
        STAGE(pB0, s3);
      }
    }
    if (t < NT - 2) asm volatile("s_waitcnt vmcnt(6)" ::: "memory");
    else            asm volatile("s_waitcnt vmcnt(0)" ::: "memory");
    __builtin_amdgcn_s_barrier();
    iA += 4; if (iA >= 10) iA -= 10;
    iB += 4; if (iB >= 10) iB -= 10;
    iS += 4; if (iS >= 10) iS -= 10;
  }

  // epilogue: C/D layout col = lane&15, row = (lane>>4)*4 + j
#pragma unroll
  for (int m = 0; m < 8; ++m) {
#pragma unroll
    for (int n = 0; n < 4; ++n) {
      const int col = n0 + wc * 64 + n * 16 + (lane & 15);
#pragma unroll
      for (int j = 0; j < 4; ++j) {
        const int row = m0 + wr * 128 + m * 16 + ((lane >> 4) << 2) + j;
        const float v = acc[m][n][j] + bias[col];
        if constexpr (EPI == 5) {
          const int rg = col >> 10;                     // block-uniform
          const size_t o = (size_t)row * 1024 + (col & 1023);
          if (rg == 0) outH[o] = f2bf(v);
          else if (rg == 1) outH2[o] = f2bf(v);
          else outH3[o] = f2bf(v);
        } else {
          const size_t o = (size_t)row * N + col;
          if constexpr (EPI == 2) {
            const float gt = bf2f(gate[o]);
            outF[o] = v * (gt / (1.f + __expf(-gt))) + resid[o];
          } else if constexpr (EPI == 6) {
            outH[o] = f2bf(v / (1.f + __expf(-v)));
          } else if constexpr (EPI == 7) {
            outH[o] = f2bf(v * bf2f(gate[o]));          // gate==outH ok (RAW per elem)
          } else if constexpr (EPI == 4) {
            outF[o] = v + outF[o];
          }
        }
      }
    }
  }
#undef STAGE
#undef READA
#undef READB
#undef MMAQ
}

extern "C" void kernel_launch(void* const* d_in, const int* in_sizes, int n_in,
                              void* d_out, int out_size, void* d_ws, size_t ws_size,
                              hipStream_t stream) {
  const float* x      = (const float*)d_in[0];
  const float* hidden = (const float*)d_in[1];
  const float* w_ln_z = (const float*)d_in[2];
  const float* b_ln_z = (const float*)d_in[3];
  const float* w_dt   = (const float*)d_in[4];
  const float* b_dt   = (const float*)d_in[5];
  const float* w_y    = (const float*)d_in[6];
  const float* b_y    = (const float*)d_in[7];
  const float* w_yg   = (const float*)d_in[8];
  const float* b_yg   = (const float*)d_in[9];
  const float* w_ff   = (const float*)d_in[10];
  const float* b_ff   = (const float*)d_in[11];
  const float* w_ffg  = (const float*)d_in[12];
  const float* b_ffg  = (const float*)d_in[13];
  const float* w_ffo  = (const float*)d_in[14];
  const float* b_ffo  = (const float*)d_in[15];
  const float* g_sio  = (const float*)d_in[16];
  const float* g_ffn  = (const float*)d_in[17];

  char* ws = (char*)d_ws;
  const size_t MB = 1ull << 20;
  u16*   WT_cat = (u16*)(ws + 0 * MB);      // 6 MiB  [3072][1024] (dt|lnz|yg)
  u16*   WT_y   = (u16*)(ws + 8 * MB);      // 2 MiB
  u16*   WT_ff  = (u16*)(ws + 10 * MB);     // 8 MiB  [4096][1024]
  u16*   WT_ffg = (u16*)(ws + 18 * MB);     // 8 MiB
  u16*   WT_ffo = (u16*)(ws + 26 * MB);     // 8 MiB  [1024][4096]
  float* b_cat  = (float*)(ws + 34 * MB);   // 12 KiB [3072]
  u16*   xn     = (u16*)(ws + 36 * MB);     // 32 MiB [16384][1024] bf16
  u16*   dt16   = (u16*)(ws + 68 * MB);     // 32 MiB bf16
  u16*   lnzb   = (u16*)(ws + 100 * MB);    // 32 MiB
  u16*   ygb    = (u16*)(ws + 132 * MB);    // 32 MiB
  u16*   hbf    = (u16*)(ws + 164 * MB);    // 32 MiB
  float* Pc     = (float*)(ws + 196 * MB);  // 1 MiB
  float* Sc     = (float*)(ws + 197 * MB);  // 1 MiB
  float* hin    = (float*)(ws + 198 * MB);  // 1 MiB
  u16*   gs     = (u16*)(ws + 68 * MB);     // 128 MiB overlay [16384][4096]
  // peak ws usage: 199 MiB

  float* x_out = (float*)d_out;
  float* h_out = (float*)d_out + (size_t)4 * 4096 * 1024;

  const int M = 16384, D = 1024, F = 4096;
  const dim3 tb(256);

  transpose_to_bf16<<<dim3(32, 32), tb, 0, stream>>>(w_dt, WT_cat, D, D);
  transpose_to_bf16<<<dim3(32, 32), tb, 0, stream>>>(w_ln_z, WT_cat + 1024 * 1024, D, D);
  transpose_to_bf16<<<dim3(32, 32), tb, 0, stream>>>(w_yg, WT_cat + 2 * 1024 * 1024, D, D);
  transpose_to_bf16<<<dim3(32, 32), tb, 0, stream>>>(w_y, WT_y, D, D);
  transpose_to_bf16<<<dim3(128, 32), tb, 0, stream>>>(w_ff, WT_ff, D, F);
  transpose_to_bf16<<<dim3(128, 32), tb, 0, stream>>>(w_ffg, WT_ffg, D, F);
  transpose_to_bf16<<<dim3(32, 128), tb, 0, stream>>>(w_ffo, WT_ffo, F, D);
  (void)hipMemcpyAsync(b_cat, b_dt, D * 4, hipMemcpyDeviceToDevice, stream);
  (void)hipMemcpyAsync(b_cat + 1024, b_ln_z, D * 4, hipMemcpyDeviceToDevice, stream);
  (void)hipMemcpyAsync(b_cat + 2048, b_yg, D * 4, hipMemcpyDeviceToDevice, stream);

  rmsnorm_kernel<<<M, tb, 0, stream>>>(x, g_sio, xn);

  // fused dt|lnz|yg GEMM: N=3072
  gemm256<5, 0><<<dim3(12 * 64), 512, 0, stream>>>(xn, WT_cat, b_cat, nullptr, nullptr,
                                                   nullptr, dt16, lnzb, ygb, 12, 3072, D);

  scan_pass1<<<1024, tb, 0, stream>>>(dt16, lnzb, Pc, Sc);
  scan_pass2<<<16, tb, 0, stream>>>(Pc, Sc, hidden, hin);
  scan_pass3<<<1024, tb, 0, stream>>>(dt16, lnzb, hin, h_out, hbf);

  // x1 = (h@w_y + b_y) * silu(yg) + x
  gemm256<2, 0><<<dim3(4 * 64), 512, 0, stream>>>(hbf, WT_y, b_y, ygb, x,
                                                  x_out, nullptr, nullptr, nullptr, 4, D, D);

  rmsnorm_kernel<<<M, tb, 0, stream>>>(x_out, g_ffn, xn);

  // gs = silu(xn@w_ffg + b_ffg)   [PROBE: SCHED=1 front-loaded reads]
  gemm256<6, 1><<<dim3(16 * 64), 512, 0, stream>>>(xn, WT_ffg, b_ffg, nullptr, nullptr,
                                                   nullptr, gs, nullptr, nullptr, 16, F, D);
  // gs = (xn@w_ff + b_ff) * gs   (in-place gated mul)  [control]
  gemm256<7, 0><<<dim3(16 * 64), 512, 0, stream>>>(xn, WT_ff, b_ff, gs, nullptr,
                                                   nullptr, gs, nullptr, nullptr, 16, F, D);
  // x_out += gs@w_ffo + b_ffo
  gemm256<4, 0><<<dim3(4 * 64), 512, 0, stream>>>(gs, WT_ffo, b_ffo, nullptr, nullptr,
                                                  x_out, nullptr, nullptr, nullptr, 4, D, F);
}